// Round 1
// baseline (1818.545 us; speedup 1.0000x reference)
//
#include <hip/hip_runtime.h>
#include <hip/hip_bf16.h>
#include <math.h>

typedef float f32x4 __attribute__((ext_vector_type(4)));
typedef __bf16 bf16x8 __attribute__((ext_vector_type(8)));

#define T_N 64
#define HW_N 729
#define M_N 512
#define DM 1152
#define NH 8
#define DH 144
#define MQ 32768        /* T*M rows */
#define MK 46656        /* T*HW rows */
#define MK_PAD 46720    /* padded to multiple of 128 (365 tiles) */

// ---- workspace layout (bytes) ----
#define SZ_FEAT ((size_t)MK_PAD * DM * 2)
#define SZ_Q    ((size_t)MQ * DM * 2)
#define SZ_W    ((size_t)DM * DM * 2)
#define OFF_FEAT ((size_t)0)
#define OFF_KN   (OFF_FEAT + SZ_FEAT)
#define OFF_AQ   (OFF_KN + SZ_FEAT)      /* track_tokens bf16; later reused for sampled */
#define OFF_QN   (OFF_AQ + SZ_Q)
#define OFF_WT   (OFF_QN + SZ_Q)
#define WS_NEED  (OFF_WT + 3 * SZ_W)

// ---------------- fp32 -> bf16 convert (with zero padding) ----------------
__global__ __launch_bounds__(256) void cvt_bf16(const float* __restrict__ src,
                                                __bf16* __restrict__ dst,
                                                long valid4, long total4) {
    long i = (long)blockIdx.x * 256 + threadIdx.x;
    if (i >= total4) return;
    float4 f = {0.f, 0.f, 0.f, 0.f};
    if (i < valid4) f = ((const float4*)src)[i];
    __bf16 tmp[4] = {(__bf16)f.x, (__bf16)f.y, (__bf16)f.z, (__bf16)f.w};
    *((uint2*)(dst + i * 4)) = *((uint2*)tmp);
}

// ---------------- W [K][N] fp32 -> Wt [N][K] bf16 ----------------
__global__ __launch_bounds__(256) void transpose_w(const float* __restrict__ W,
                                                   __bf16* __restrict__ Wt) {
    __shared__ float tile[32][33];
    const int k0 = blockIdx.x * 32, n0 = blockIdx.y * 32;
    const int tx = threadIdx.x, ty = threadIdx.y; // 32 x 8
    #pragma unroll
    for (int i = 0; i < 32; i += 8)
        tile[ty + i][tx] = W[(long)(k0 + ty + i) * DM + n0 + tx];
    __syncthreads();
    #pragma unroll
    for (int i = 0; i < 32; i += 8)
        Wt[(long)(n0 + ty + i) * DM + k0 + tx] = (__bf16)tile[tx][ty + i];
}

// ---------------- bf16 MFMA GEMM: C[M,N] = A[M,K] * Bt[N,K]^T ----------------
// 128x128 tile, BK=32, 256 threads = 4 waves in 2x2, each wave 64x64 (4x4 MFMA tiles)
template<bool STORE_BF16>
__global__ __launch_bounds__(256) void gemm_bt(const __bf16* __restrict__ A,
                                               const __bf16* __restrict__ Bt,
                                               void* __restrict__ Cout) {
    __shared__ __align__(16) __bf16 As[128 * 40]; // stride 40 kills bank conflicts
    __shared__ __align__(16) __bf16 Bs[128 * 40];
    const int tid  = threadIdx.x;
    const int wave = tid >> 6, lane = tid & 63;
    const int quad = lane >> 4, l16 = lane & 15;
    const int wr = wave >> 1, wc = wave & 1;
    const long m0 = (long)blockIdx.x * 128;
    const long n0 = (long)blockIdx.y * 128;
    f32x4 acc[4][4] = {};
    for (int kt = 0; kt < 36; ++kt) {
        const int k0 = kt * 32;
        __syncthreads();
        #pragma unroll
        for (int s = 0; s < 2; ++s) {
            const int c = s * 256 + tid;       // 512 chunks of 16B
            const int row = c >> 2, kc = c & 3;
            uint4 va = *(const uint4*)(A  + (m0 + row) * DM + k0 + kc * 8);
            uint4 vb = *(const uint4*)(Bt + (n0 + row) * DM + k0 + kc * 8);
            *(uint4*)(As + row * 40 + kc * 8) = va;
            *(uint4*)(Bs + row * 40 + kc * 8) = vb;
        }
        __syncthreads();
        bf16x8 af[4], bfr[4];
        #pragma unroll
        for (int i = 0; i < 4; ++i)
            af[i] = *(const bf16x8*)(As + (wr * 64 + i * 16 + l16) * 40 + quad * 8);
        #pragma unroll
        for (int j = 0; j < 4; ++j)
            bfr[j] = *(const bf16x8*)(Bs + (wc * 64 + j * 16 + l16) * 40 + quad * 8);
        #pragma unroll
        for (int i = 0; i < 4; ++i)
            #pragma unroll
            for (int j = 0; j < 4; ++j)
                acc[i][j] = __builtin_amdgcn_mfma_f32_16x16x32_bf16(af[i], bfr[j], acc[i][j], 0, 0, 0);
    }
    // epilogue: D row=(quad*4+r) (M), col=l16 (N)  [verified C/D layout]
    #pragma unroll
    for (int i = 0; i < 4; ++i) {
        #pragma unroll
        for (int j = 0; j < 4; ++j) {
            #pragma unroll
            for (int r = 0; r < 4; ++r) {
                const long row = m0 + wr * 64 + i * 16 + quad * 4 + r;
                const long col = n0 + wc * 64 + j * 16 + l16;
                if constexpr (STORE_BF16)
                    ((__bf16*)Cout)[row * DM + col] = (__bf16)acc[i][j][r];
                else
                    ((float*)Cout)[row * DM + col] = acc[i][j][r];
            }
        }
    }
}

// ---------------- LayerNorm (no bias) over 1152, in-place bf16 ----------------
__global__ __launch_bounds__(256) void ln_q(__bf16* __restrict__ Q, const float* __restrict__ w) {
    const long row = blockIdx.x;
    __bf16* p = Q + row * DM;
    const int tid = threadIdx.x;
    float v[5];
    int nv = 0;
    float s = 0.f, s2 = 0.f;
    for (int i = tid; i < DM; i += 256) {
        float x = (float)p[i];
        v[nv++] = x; s += x; s2 += x * x;
    }
    #pragma unroll
    for (int o = 32; o > 0; o >>= 1) { s += __shfl_down(s, o); s2 += __shfl_down(s2, o); }
    __shared__ float red[8];
    if ((tid & 63) == 0) { red[tid >> 6] = s; red[4 + (tid >> 6)] = s2; }
    __syncthreads();
    const float S  = red[0] + red[1] + red[2] + red[3];
    const float S2 = red[4] + red[5] + red[6] + red[7];
    const float mu  = S * (1.f / DM);
    const float var = S2 * (1.f / DM) - mu * mu;
    const float rstd = rsqrtf(var + 1e-6f);
    nv = 0;
    for (int i = tid; i < DM; i += 256)
        p[i] = (__bf16)((v[nv++] - mu) * rstd * w[i]);
}

// ---------------- RoPE-2D (full 1152 dim) + LayerNorm, in-place bf16 ----------------
__global__ __launch_bounds__(256) void rope_ln_k(__bf16* __restrict__ K,
                                                 const float* __restrict__ fpos,
                                                 const float* __restrict__ w) {
    const long row = blockIdx.x;            // 0..46655 = t*729+hw
    const int hw = (int)(row % HW_N);
    const float px = fpos[hw * 2 + 0];
    const float py = fpos[hw * 2 + 1];
    __bf16* p = K + row * DM;
    __shared__ float buf[DM];
    __shared__ float red[8];
    const int tid = threadIdx.x;
    float s = 0.f, s2 = 0.f;
    for (int pr = tid; pr < 576; pr += 256) {   // 288 x-pairs then 288 y-pairs
        const bool isx = pr < 288;
        const int  i   = isx ? pr : pr - 288;
        const int  off = isx ? 2 * i : 576 + 2 * i;
        const float pos = isx ? px : py;
        const float theta = powf(10000.f, -(float)i * (1.f / 288.f));
        float sn, cs;
        sincosf(pos * theta, &sn, &cs);
        const float a = (float)p[off], b = (float)p[off + 1];
        const float o1 = a * cs - b * sn;
        const float o2 = a * sn + b * cs;
        buf[off] = o1; buf[off + 1] = o2;
        s += o1 + o2; s2 += o1 * o1 + o2 * o2;
    }
    #pragma unroll
    for (int o = 32; o > 0; o >>= 1) { s += __shfl_down(s, o); s2 += __shfl_down(s2, o); }
    if ((tid & 63) == 0) { red[tid >> 6] = s; red[4 + (tid >> 6)] = s2; }
    __syncthreads();
    const float S  = red[0] + red[1] + red[2] + red[3];
    const float S2 = red[4] + red[5] + red[6] + red[7];
    const float mu  = S * (1.f / DM);
    const float var = S2 * (1.f / DM) - mu * mu;
    const float rstd = rsqrtf(var + 1e-6f);
    for (int i = tid; i < DM; i += 256)
        p[i] = (__bf16)((buf[i] - mu) * rstd * w[i]);
}

// ---------------- flash attention + gaussian spatial bias ----------------
// grid: 4096 = (t*8+h)*8 + qt ; block 256 = 4 waves, each wave 16 q-rows; KV tile 32
__global__ __launch_bounds__(256) void attn(const __bf16* __restrict__ Qn,
                                            const __bf16* __restrict__ Kn,
                                            const __bf16* __restrict__ Vf,
                                            const float* __restrict__ tracks,
                                            const float* __restrict__ fpos,
                                            __bf16* __restrict__ Out) {
    const int b  = blockIdx.x;
    const int qt = b & 7;
    const int th = b >> 3;
    const int h  = th & 7;
    const int t  = th >> 3;
    __shared__ __align__(16) __bf16 Qs[64 * 168]; // 64 q-rows x 160 (dh padded), stride 168
    __shared__ __align__(16) __bf16 Ks[32 * 168];
    __shared__ __align__(16) __bf16 Vs[32 * 168];
    __shared__ __align__(16) __bf16 Ps[64 * 40];  // P tile, stride 40
    __shared__ float trkx[64], trky[64], fpx[32], fpy[32];
    const int tid = threadIdx.x;
    const int wave = tid >> 6, lane = tid & 63;
    const int quad = lane >> 4, l16 = lane & 15;

    { // stage Q tile once (cols 144..159 zeroed)
        const __bf16* qb = Qn + ((long)t * M_N + qt * 64) * DM + h * DH;
        for (int c = tid; c < 64 * 20; c += 256) {
            const int r = c / 20, cc = c % 20;
            uint4 v = {0u, 0u, 0u, 0u};
            if (cc < 18) v = *(const uint4*)(qb + (long)r * DM + cc * 8);
            *(uint4*)(Qs + r * 168 + cc * 8) = v;
        }
        if (tid < 64) {
            const long qr = (long)t * M_N + qt * 64 + tid;
            trkx[tid] = tracks[qr * 2 + 0];
            trky[tid] = tracks[qr * 2 + 1];
        }
    }

    float mrow[4], lrow[4];
    #pragma unroll
    for (int r = 0; r < 4; ++r) { mrow[r] = -1e30f; lrow[r] = 0.f; }
    f32x4 Ot[9] = {};

    for (int kt = 0; kt < 23; ++kt) {
        const int kv0 = kt * 32;
        __syncthreads();
        { // stage K/V tiles (zero pad cols >=144; rows past HW are masked via bias)
            const __bf16* kb = Kn + ((long)t * HW_N + kv0) * DM + h * DH;
            const __bf16* vb = Vf + ((long)t * HW_N + kv0) * DM + h * DH;
            for (int c = tid; c < 32 * 20; c += 256) {
                const int r = c / 20, cc = c % 20;
                uint4 vk = {0u,0u,0u,0u}, vv = {0u,0u,0u,0u};
                if (cc < 18) {
                    vk = *(const uint4*)(kb + (long)r * DM + cc * 8);
                    vv = *(const uint4*)(vb + (long)r * DM + cc * 8);
                }
                *(uint4*)(Ks + r * 168 + cc * 8) = vk;
                *(uint4*)(Vs + r * 168 + cc * 8) = vv;
            }
            if (tid < 32) {
                const int hw = kv0 + tid;
                if (hw < HW_N) { fpx[tid] = fpos[hw * 2]; fpy[tid] = fpos[hw * 2 + 1]; }
                else           { fpx[tid] = 0.f;          fpy[tid] = 0.f; }
            }
        }
        __syncthreads();
        // --- S = Q K^T ---
        f32x4 sc[2] = {};
        #pragma unroll
        for (int kc = 0; kc < 5; ++kc) {
            const bf16x8 aq = *(const bf16x8*)(Qs + (wave * 16 + l16) * 168 + kc * 32 + quad * 8);
            #pragma unroll
            for (int j = 0; j < 2; ++j) {
                const bf16x8 bk = *(const bf16x8*)(Ks + (j * 16 + l16) * 168 + kc * 32 + quad * 8);
                sc[j] = __builtin_amdgcn_mfma_f32_16x16x32_bf16(aq, bk, sc[j], 0, 0, 0);
            }
        }
        // --- bias + online softmax (rows = quad*4+r, cols = j*16+l16) ---
        float fx[2], fy[2]; bool msk[2];
        #pragma unroll
        for (int j = 0; j < 2; ++j) {
            const int cl = j * 16 + l16;
            fx[j] = fpx[cl]; fy[j] = fpy[cl];
            msk[j] = (kv0 + cl) >= HW_N;
        }
        float pvals[4][2];
        float alpha[4];
        #pragma unroll
        for (int r = 0; r < 4; ++r) {
            const int brow = wave * 16 + quad * 4 + r;
            const float tx = trkx[brow], ty = trky[brow];
            float mx = -1e30f;
            #pragma unroll
            for (int j = 0; j < 2; ++j) {
                const float dx = tx - fx[j], dy = ty - fy[j];
                float sv = sc[j][r] * (1.f / 12.f) - (dx * dx + dy * dy) * 0.125f;
                if (msk[j]) sv = -1e30f;
                pvals[r][j] = sv;
                mx = fmaxf(mx, sv);
            }
            #pragma unroll
            for (int o = 1; o < 16; o <<= 1) mx = fmaxf(mx, __shfl_xor(mx, o));
            const float mn = fmaxf(mrow[r], mx);
            alpha[r] = __expf(mrow[r] - mn);
            float rs = 0.f;
            #pragma unroll
            for (int j = 0; j < 2; ++j) {
                const float pv = __expf(pvals[r][j] - mn);
                pvals[r][j] = pv; rs += pv;
            }
            #pragma unroll
            for (int o = 1; o < 16; o <<= 1) rs += __shfl_xor(rs, o);
            lrow[r] = lrow[r] * alpha[r] + rs;
            mrow[r] = mn;
        }
        #pragma unroll
        for (int d = 0; d < 9; ++d)
            #pragma unroll
            for (int r = 0; r < 4; ++r)
                Ot[d][r] *= alpha[r];
        // P -> LDS (C-layout to A-operand layout round trip)
        #pragma unroll
        for (int r = 0; r < 4; ++r)
            #pragma unroll
            for (int j = 0; j < 2; ++j)
                Ps[(wave * 16 + quad * 4 + r) * 40 + j * 16 + l16] = (__bf16)pvals[r][j];
        __syncthreads();
        // --- O += P V ---
        const bf16x8 ap = *(const bf16x8*)(Ps + (wave * 16 + l16) * 40 + quad * 8);
        #pragma unroll
        for (int d = 0; d < 9; ++d) {
            bf16x8 bv;
            #pragma unroll
            for (int jj = 0; jj < 8; ++jj)
                bv[jj] = Vs[(quad * 8 + jj) * 168 + d * 16 + l16]; // V^T gather (scalar; optimize later)
            Ot[d] = __builtin_amdgcn_mfma_f32_16x16x32_bf16(ap, bv, Ot[d], 0, 0, 0);
        }
    }
    // epilogue: sampled[t, m, h*144 + dh]
    #pragma unroll
    for (int d = 0; d < 9; ++d) {
        #pragma unroll
        for (int r = 0; r < 4; ++r) {
            const long row = (long)t * M_N + qt * 64 + wave * 16 + quad * 4 + r;
            Out[row * DM + h * DH + d * 16 + l16] = (__bf16)(Ot[d][r] / lrow[r]);
        }
    }
}

extern "C" void kernel_launch(void* const* d_in, const int* in_sizes, int n_in,
                              void* d_out, int out_size, void* d_ws, size_t ws_size,
                              hipStream_t stream) {
    const float* features   = (const float*)d_in[0];
    const float* tracks     = (const float*)d_in[1];
    const float* tok        = (const float*)d_in[2];
    const float* fpos       = (const float*)d_in[3];
    const float* W_q        = (const float*)d_in[4];
    const float* W_k        = (const float*)d_in[5];
    const float* q_w        = (const float*)d_in[6];
    const float* k_w        = (const float*)d_in[7];
    const float* W_o        = (const float*)d_in[8];

    if (ws_size < WS_NEED) return; // signature failure mode: absmax == max|ref|

    char* ws = (char*)d_ws;
    __bf16* feat_bf = (__bf16*)(ws + OFF_FEAT);
    __bf16* kn      = (__bf16*)(ws + OFF_KN);
    __bf16* tok_bf  = (__bf16*)(ws + OFF_AQ);   // reused as `sampled` after Q-proj
    __bf16* qn      = (__bf16*)(ws + OFF_QN);
    __bf16* wt_q    = (__bf16*)(ws + OFF_WT);
    __bf16* wt_k    = (__bf16*)(ws + OFF_WT + SZ_W);
    __bf16* wt_o    = (__bf16*)(ws + OFF_WT + 2 * SZ_W);

    // converts (features zero-padded to MK_PAD rows)
    {
        const long valid4 = (long)MK * DM / 4, total4 = (long)MK_PAD * DM / 4;
        cvt_bf16<<<(int)((total4 + 255) / 256), 256, 0, stream>>>(features, feat_bf, valid4, total4);
    }
    {
        const long n4 = (long)MQ * DM / 4;
        cvt_bf16<<<(int)((n4 + 255) / 256), 256, 0, stream>>>(tok, tok_bf, n4, n4);
    }
    // weight transposes
    dim3 tb(32, 8);
    transpose_w<<<dim3(36, 36), tb, 0, stream>>>(W_q, wt_q);
    transpose_w<<<dim3(36, 36), tb, 0, stream>>>(W_k, wt_k);
    transpose_w<<<dim3(36, 36), tb, 0, stream>>>(W_o, wt_o);

    // projections
    gemm_bt<true><<<dim3(MQ / 128, DM / 128), 256, 0, stream>>>(tok_bf, wt_q, qn);
    gemm_bt<true><<<dim3(MK_PAD / 128, DM / 128), 256, 0, stream>>>(feat_bf, wt_k, kn);

    // norms (+RoPE for K)
    ln_q<<<MQ, 256, 0, stream>>>(qn, q_w);
    rope_ln_k<<<MK, 256, 0, stream>>>(kn, fpos, k_w);

    // attention -> sampled (reuses tok_bf region)
    __bf16* sampled = tok_bf;
    attn<<<T_N * NH * (M_N / 64), 256, 0, stream>>>(qn, kn, feat_bf, tracks, fpos, sampled);

    // output projection -> d_out (fp32)
    gemm_bt<false><<<dim3(MQ / 128, DM / 128), 256, 0, stream>>>(sampled, wt_o, d_out);
}

// Round 2
// 1739.009 us; speedup vs baseline: 1.0457x; 1.0457x over previous
//
#include <hip/hip_runtime.h>
#include <hip/hip_bf16.h>
#include <math.h>

typedef float f32x4 __attribute__((ext_vector_type(4)));
typedef __bf16 bf16x8 __attribute__((ext_vector_type(8)));

#define T_N 64
#define HW_N 729
#define HW_P 736        /* padded hw for Vt (16B-aligned rows) */
#define M_N 512
#define DM 1152
#define NH 8
#define DH 144
#define MQ 32768        /* T*M rows */
#define MK 46656        /* T*HW rows */
#define MK_PAD 46720    /* padded to multiple of 128 (365 tiles) */

// ---- workspace layout (bytes); Vt overlays feat_bf (dead after K-proj) ----
#define SZ_FEAT ((size_t)MK_PAD * DM * 2)
#define SZ_VT   ((size_t)T_N * NH * DH * HW_P * 2)
#define SZ_OV   (SZ_VT > SZ_FEAT ? SZ_VT : SZ_FEAT)
#define SZ_Q    ((size_t)MQ * DM * 2)
#define SZ_W    ((size_t)DM * DM * 2)
#define OFF_KN   ((size_t)0)
#define OFF_TOK  (OFF_KN + SZ_FEAT)
#define OFF_QN   (OFF_TOK + SZ_Q)
#define OFF_OV   (OFF_QN + SZ_Q)
#define OFF_WT   (OFF_OV + SZ_OV)
#define WS_NEED  (OFF_WT + 3 * SZ_W)

// async global->LDS 16B (wave-uniform base + lane*16 placement)
__device__ __forceinline__ void async_copy16(void* lds, const void* g) {
    __builtin_amdgcn_global_load_lds(
        (const __attribute__((address_space(1))) void*)g,
        (__attribute__((address_space(3))) void*)lds, 16, 0, 0);
}

// ---------------- fp32 -> bf16 convert (with zero padding) ----------------
__global__ __launch_bounds__(256) void cvt_bf16(const float* __restrict__ src,
                                                __bf16* __restrict__ dst,
                                                long valid4, long total4) {
    long i = (long)blockIdx.x * 256 + threadIdx.x;
    if (i >= total4) return;
    float4 f = {0.f, 0.f, 0.f, 0.f};
    if (i < valid4) f = ((const float4*)src)[i];
    __bf16 tmp[4] = {(__bf16)f.x, (__bf16)f.y, (__bf16)f.z, (__bf16)f.w};
    *((uint2*)(dst + i * 4)) = *((uint2*)tmp);
}

// ---------------- W [K][N] fp32 -> Wt [N][K] bf16 ----------------
__global__ __launch_bounds__(256) void transpose_w(const float* __restrict__ W,
                                                   __bf16* __restrict__ Wt) {
    __shared__ float tile[32][33];
    const int k0 = blockIdx.x * 32, n0 = blockIdx.y * 32;
    const int tx = threadIdx.x, ty = threadIdx.y; // 32 x 8
    #pragma unroll
    for (int i = 0; i < 32; i += 8)
        tile[ty + i][tx] = W[(long)(k0 + ty + i) * DM + n0 + tx];
    __syncthreads();
    #pragma unroll
    for (int i = 0; i < 32; i += 8)
        Wt[(long)(n0 + ty + i) * DM + k0 + tx] = (__bf16)tile[tx][ty + i];
}

// ---- V transpose: features fp32 [t][hw][1152] -> Vt bf16 [t*8+h][dh 144][hw 736] ----
__global__ __launch_bounds__(256) void transpose_v(const float* __restrict__ f,
                                                   __bf16* __restrict__ vt) {
    __shared__ float tile[32][149];
    const int hw0 = blockIdx.x * 32, h = blockIdx.y, t = blockIdx.z;
    const int tid = threadIdx.x;
    for (int c = tid; c < 32 * 36; c += 256) {
        const int r = c / 36, s = c % 36;
        const int hw = hw0 + r;
        float4 v = {0.f, 0.f, 0.f, 0.f};
        if (hw < HW_N) v = *(const float4*)(f + ((long)t * HW_N + hw) * DM + h * DH + s * 4);
        tile[r][s * 4 + 0] = v.x; tile[r][s * 4 + 1] = v.y;
        tile[r][s * 4 + 2] = v.z; tile[r][s * 4 + 3] = v.w;
    }
    __syncthreads();
    for (int c = tid; c < DH * 4; c += 256) {   // 144 rows x 4 chunks of 8 hw
        const int d = c >> 2, s = c & 3;
        __bf16 tmp[8];
        #pragma unroll
        for (int i = 0; i < 8; ++i) tmp[i] = (__bf16)tile[s * 8 + i][d];
        *(uint4*)(vt + ((long)(t * NH + h) * DH + d) * HW_P + hw0 + s * 8) = *(uint4*)tmp;
    }
}

// ---------------- bf16 MFMA GEMM: C[M,N] = A[M,K] * Bt[N,K]^T ----------------
// 128x128 tile, BK=32, global_load_lds staging + XOR slot swizzle (conflict-free)
template<bool STORE_BF16>
__global__ __launch_bounds__(256) void gemm_bt(const __bf16* __restrict__ A,
                                               const __bf16* __restrict__ Bt,
                                               void* __restrict__ Cout) {
    __shared__ __align__(16) __bf16 As[128 * 32];
    __shared__ __align__(16) __bf16 Bs[128 * 32];
    const int tid  = threadIdx.x;
    const int wave = tid >> 6, lane = tid & 63;
    const int quad = lane >> 4, l16 = lane & 15;
    const int wr = wave >> 1, wc = wave & 1;
    const long m0 = (long)blockIdx.x * 128;
    const long n0 = (long)blockIdx.y * 128;
    const int swzr = quad ^ ((l16 >> 1) & 3);   // frag-read slot swizzle
    f32x4 acc[4][4] = {};
    for (int kt = 0; kt < 36; ++kt) {
        const int k0 = kt * 32;
        __syncthreads();
        #pragma unroll
        for (int s = 0; s < 2; ++s) {
            const int c = s * 256 + tid;        // 512 chunks of 16B each matrix
            const int row = c >> 2;
            const int gkc = (c & 3) ^ ((c >> 3) & 3);   // slot->global kc swizzle
            async_copy16(As + c * 8, A  + (m0 + row) * DM + k0 + gkc * 8);
            async_copy16(Bs + c * 8, Bt + (n0 + row) * DM + k0 + gkc * 8);
        }
        __syncthreads();
        bf16x8 af[4], bfr[4];
        #pragma unroll
        for (int i = 0; i < 4; ++i)
            af[i] = *(const bf16x8*)(As + (wr * 64 + i * 16 + l16) * 32 + swzr * 8);
        #pragma unroll
        for (int j = 0; j < 4; ++j)
            bfr[j] = *(const bf16x8*)(Bs + (wc * 64 + j * 16 + l16) * 32 + swzr * 8);
        #pragma unroll
        for (int i = 0; i < 4; ++i)
            #pragma unroll
            for (int j = 0; j < 4; ++j)
                acc[i][j] = __builtin_amdgcn_mfma_f32_16x16x32_bf16(af[i], bfr[j], acc[i][j], 0, 0, 0);
    }
    #pragma unroll
    for (int i = 0; i < 4; ++i) {
        #pragma unroll
        for (int j = 0; j < 4; ++j) {
            #pragma unroll
            for (int r = 0; r < 4; ++r) {
                const long row = m0 + wr * 64 + i * 16 + quad * 4 + r;
                const long col = n0 + wc * 64 + j * 16 + l16;
                if constexpr (STORE_BF16)
                    ((__bf16*)Cout)[row * DM + col] = (__bf16)acc[i][j][r];
                else
                    ((float*)Cout)[row * DM + col] = acc[i][j][r];
            }
        }
    }
}

// ---------------- LayerNorm (no bias) over 1152, in-place bf16 ----------------
__global__ __launch_bounds__(256) void ln_q(__bf16* __restrict__ Q, const float* __restrict__ w) {
    const long row = blockIdx.x;
    __bf16* p = Q + row * DM;
    const int tid = threadIdx.x;
    float v[5];
    int nv = 0;
    float s = 0.f, s2 = 0.f;
    for (int i = tid; i < DM; i += 256) {
        float x = (float)p[i];
        v[nv++] = x; s += x; s2 += x * x;
    }
    #pragma unroll
    for (int o = 32; o > 0; o >>= 1) { s += __shfl_down(s, o); s2 += __shfl_down(s2, o); }
    __shared__ float red[8];
    if ((tid & 63) == 0) { red[tid >> 6] = s; red[4 + (tid >> 6)] = s2; }
    __syncthreads();
    const float S  = red[0] + red[1] + red[2] + red[3];
    const float S2 = red[4] + red[5] + red[6] + red[7];
    const float mu  = S * (1.f / DM);
    const float var = S2 * (1.f / DM) - mu * mu;
    const float rstd = rsqrtf(var + 1e-6f);
    nv = 0;
    for (int i = tid; i < DM; i += 256)
        p[i] = (__bf16)((v[nv++] - mu) * rstd * w[i]);
}

// ---------------- RoPE-2D (full 1152 dim) + LayerNorm, in-place bf16 ----------------
__global__ __launch_bounds__(256) void rope_ln_k(__bf16* __restrict__ K,
                                                 const float* __restrict__ fpos,
                                                 const float* __restrict__ w) {
    const long row = blockIdx.x;            // 0..46655 = t*729+hw
    const int hw = (int)(row % HW_N);
    const float px = fpos[hw * 2 + 0];
    const float py = fpos[hw * 2 + 1];
    __bf16* p = K + row * DM;
    __shared__ float buf[DM];
    __shared__ float red[8];
    const int tid = threadIdx.x;
    float s = 0.f, s2 = 0.f;
    for (int pr = tid; pr < 576; pr += 256) {   // 288 x-pairs then 288 y-pairs
        const bool isx = pr < 288;
        const int  i   = isx ? pr : pr - 288;
        const int  off = isx ? 2 * i : 576 + 2 * i;
        const float pos = isx ? px : py;
        const float theta = exp2f((float)i * -0.046137890206768924f); // 10000^(-i/288)
        float sn, cs;
        sincosf(pos * theta, &sn, &cs);
        const float a = (float)p[off], b = (float)p[off + 1];
        const float o1 = a * cs - b * sn;
        const float o2 = a * sn + b * cs;
        buf[off] = o1; buf[off + 1] = o2;
        s += o1 + o2; s2 += o1 * o1 + o2 * o2;
    }
    #pragma unroll
    for (int o = 32; o > 0; o >>= 1) { s += __shfl_down(s, o); s2 += __shfl_down(s2, o); }
    if ((tid & 63) == 0) { red[tid >> 6] = s; red[4 + (tid >> 6)] = s2; }
    __syncthreads();
    const float S  = red[0] + red[1] + red[2] + red[3];
    const float S2 = red[4] + red[5] + red[6] + red[7];
    const float mu  = S * (1.f / DM);
    const float var = S2 * (1.f / DM) - mu * mu;
    const float rstd = rsqrtf(var + 1e-6f);
    for (int i = tid; i < DM; i += 256)
        p[i] = (__bf16)((buf[i] - mu) * rstd * w[i]);
}

// ---------------- flash attention + gaussian spatial bias ----------------
// grid 2048 = ((t*8+h)*4 + qt); block 256 = 4 waves; wave: 32 q-rows (2 rowtiles); KV tile 64
__global__ __launch_bounds__(256, 3) void attn(const __bf16* __restrict__ Qn,
                                               const __bf16* __restrict__ Kn,
                                               const __bf16* __restrict__ Vt,
                                               const float* __restrict__ tracks,
                                               const float* __restrict__ fpos,
                                               __bf16* __restrict__ Out) {
    __shared__ __align__(16) __bf16 VtL[DH * 72];   // V^T tile [dh 144][kv 64 +8 pad]
    __shared__ __align__(16) __bf16 Ps[128 * 72];   // P tile [128 q][kv 64 +8 pad]
    __shared__ float2 trkL[128];
    const int b  = blockIdx.x;
    const int qt = b & 3;
    const int th = b >> 2;
    const int h  = th & 7;
    const int t  = th >> 3;
    const int tid = threadIdx.x;
    const int wave = tid >> 6, lane = tid & 63;
    const int quad = lane >> 4, l16 = lane & 15;
    const int wq = wave * 32;                        // wave's q-row base within block

    if (tid < 128) trkL[tid] = ((const float2*)tracks)[(long)t * M_N + qt * 128 + tid];

    const __bf16* qb = Qn + ((long)t * M_N + qt * 128 + wq) * DM + h * DH;
    const __bf16* kb = Kn + (long)t * HW_N * DM + h * DH;
    const __bf16* vb = Vt + (long)(t * NH + h) * DH * HW_P;
    const __bf16* zpg = Kn + (size_t)MK * DM;        // known-zero rows (gemm pad output)

    f32x4 Ot[2][9] = {};
    float mrow[2][4], lrow[2][4];
    #pragma unroll
    for (int rt = 0; rt < 2; ++rt)
        #pragma unroll
        for (int r = 0; r < 4; ++r) { mrow[rt][r] = -1e30f; lrow[rt][r] = 0.f; }

    for (int kt = 0; kt < 12; ++kt) {
        const int kv0 = kt * 64;
        __syncthreads();                             // VtL reuse guard (also trkL visibility)
        // stage V^T tile: 144 rows x 9 chunks (8 data + 1 pad-from-zero-page)
        for (int c = tid; c < DH * 9; c += 256) {
            const int r = c / 9, s = c % 9;
            const __bf16* g = (s < 8 && (kv0 + s * 8 + 8) <= HW_P)
                                ? vb + (long)r * HW_P + kv0 + s * 8 : zpg;
            async_copy16(VtL + c * 8, g);
        }
        __syncthreads();
        // --- S = Q K^T (Q frags from L1, K b-frags direct-global) ---
        f32x4 sc[2][4] = {};
        #pragma unroll
        for (int kc = 0; kc < 5; ++kc) {
            bf16x8 aq[2];
            #pragma unroll
            for (int rt = 0; rt < 2; ++rt) {
                uint4 u = {0u, 0u, 0u, 0u};
                if (kc < 4 || quad < 2)
                    u = *(const uint4*)(qb + (long)(rt * 16 + l16) * DM + kc * 32 + quad * 8);
                aq[rt] = *(bf16x8*)&u;
            }
            #pragma unroll
            for (int jt = 0; jt < 4; ++jt) {
                const bf16x8 bk = *(const bf16x8*)(kb + (long)(kv0 + jt * 16 + l16) * DM + kc * 32 + quad * 8);
                #pragma unroll
                for (int rt = 0; rt < 2; ++rt)
                    sc[rt][jt] = __builtin_amdgcn_mfma_f32_16x16x32_bf16(aq[rt], bk, sc[rt][jt], 0, 0, 0);
            }
        }
        // --- bias + online softmax ---
        float fx[4], fy[4]; bool msk[4];
        #pragma unroll
        for (int jt = 0; jt < 4; ++jt) {
            const int kv = kv0 + jt * 16 + l16;
            msk[jt] = kv >= HW_N;
            float2 fp = {0.f, 0.f};
            if (!msk[jt]) fp = ((const float2*)fpos)[kv];
            fx[jt] = fp.x; fy[jt] = fp.y;
        }
        float alpha[2][4];
        #pragma unroll
        for (int rt = 0; rt < 2; ++rt) {
            #pragma unroll
            for (int r = 0; r < 4; ++r) {
                const int row = wq + rt * 16 + quad * 4 + r;   // block-local q row
                const float tx = trkL[row].x, ty = trkL[row].y;
                float sv[4];
                float mx = -1e30f;
                #pragma unroll
                for (int jt = 0; jt < 4; ++jt) {
                    const float dx = tx - fx[jt], dy = ty - fy[jt];
                    float v = sc[rt][jt][r] * (1.f / 12.f) - (dx * dx + dy * dy) * 0.125f;
                    if (msk[jt]) v = -1e30f;
                    sv[jt] = v;
                    mx = fmaxf(mx, v);
                }
                #pragma unroll
                for (int o = 1; o < 16; o <<= 1) mx = fmaxf(mx, __shfl_xor(mx, o));
                const float mn = fmaxf(mrow[rt][r], mx);
                const float al = __expf(mrow[rt][r] - mn);
                float rs = 0.f;
                #pragma unroll
                for (int jt = 0; jt < 4; ++jt) {
                    const float p = __expf(sv[jt] - mn);
                    rs += p;
                    Ps[row * 72 + jt * 16 + l16] = (__bf16)p;
                }
                #pragma unroll
                for (int o = 1; o < 16; o <<= 1) rs += __shfl_xor(rs, o);
                lrow[rt][r] = lrow[rt][r] * al + rs;
                mrow[rt][r] = mn;
                alpha[rt][r] = al;
            }
        }
        #pragma unroll
        for (int rt = 0; rt < 2; ++rt)
            #pragma unroll
            for (int d = 0; d < 9; ++d)
                #pragma unroll
                for (int r = 0; r < 4; ++r)
                    Ot[rt][d][r] *= alpha[rt][r];
        __syncthreads();                             // P write -> read safety
        // --- O += P V ---
        #pragma unroll
        for (int kh = 0; kh < 2; ++kh) {
            bf16x8 ap[2];
            #pragma unroll
            for (int rt = 0; rt < 2; ++rt)
                ap[rt] = *(const bf16x8*)(Ps + (wq + rt * 16 + l16) * 72 + kh * 32 + quad * 8);
            #pragma unroll
            for (int d = 0; d < 9; ++d) {
                const bf16x8 bv = *(const bf16x8*)(VtL + (d * 16 + l16) * 72 + kh * 32 + quad * 8);
                #pragma unroll
                for (int rt = 0; rt < 2; ++rt)
                    Ot[rt][d] = __builtin_amdgcn_mfma_f32_16x16x32_bf16(ap[rt], bv, Ot[rt][d], 0, 0, 0);
            }
        }
    }
    // epilogue: sampled[t, m, h*144 + dh]
    #pragma unroll
    for (int rt = 0; rt < 2; ++rt) {
        #pragma unroll
        for (int r = 0; r < 4; ++r) {
            const float inv = 1.f / lrow[rt][r];
            const long row = (long)t * M_N + qt * 128 + wq + rt * 16 + quad * 4 + r;
            #pragma unroll
            for (int d = 0; d < 9; ++d)
                Out[row * DM + h * DH + d * 16 + l16] = (__bf16)(Ot[rt][d][r] * inv);
        }
    }
}

extern "C" void kernel_launch(void* const* d_in, const int* in_sizes, int n_in,
                              void* d_out, int out_size, void* d_ws, size_t ws_size,
                              hipStream_t stream) {
    const float* features = (const float*)d_in[0];
    const float* tracks   = (const float*)d_in[1];
    const float* tok      = (const float*)d_in[2];
    const float* fpos     = (const float*)d_in[3];
    const float* W_q      = (const float*)d_in[4];
    const float* W_k      = (const float*)d_in[5];
    const float* q_w      = (const float*)d_in[6];
    const float* k_w      = (const float*)d_in[7];
    const float* W_o      = (const float*)d_in[8];

    if (ws_size < WS_NEED) return; // failure signature: absmax == max|ref|

    char* ws = (char*)d_ws;
    __bf16* kn      = (__bf16*)(ws + OFF_KN);
    __bf16* tok_bf  = (__bf16*)(ws + OFF_TOK);  // reused as `sampled` after Q-proj
    __bf16* qn      = (__bf16*)(ws + OFF_QN);
    __bf16* feat_bf = (__bf16*)(ws + OFF_OV);   // overlay: feat_bf then Vt
    __bf16* vt      = (__bf16*)(ws + OFF_OV);
    __bf16* wt_q    = (__bf16*)(ws + OFF_WT);
    __bf16* wt_k    = (__bf16*)(ws + OFF_WT + SZ_W);
    __bf16* wt_o    = (__bf16*)(ws + OFF_WT + 2 * SZ_W);

    // converts (features zero-padded to MK_PAD rows)
    {
        const long valid4 = (long)MK * DM / 4, total4 = (long)MK_PAD * DM / 4;
        cvt_bf16<<<(int)((total4 + 255) / 256), 256, 0, stream>>>(features, feat_bf, valid4, total4);
    }
    {
        const long n4 = (long)MQ * DM / 4;
        cvt_bf16<<<(int)((n4 + 255) / 256), 256, 0, stream>>>(tok, tok_bf, n4, n4);
    }
    // weight transposes
    dim3 tb(32, 8);
    transpose_w<<<dim3(36, 36), tb, 0, stream>>>(W_q, wt_q);
    transpose_w<<<dim3(36, 36), tb, 0, stream>>>(W_k, wt_k);
    transpose_w<<<dim3(36, 36), tb, 0, stream>>>(W_o, wt_o);

    // projections
    gemm_bt<true><<<dim3(MQ / 128, DM / 128), 256, 0, stream>>>(tok_bf, wt_q, qn);
    gemm_bt<true><<<dim3(MK_PAD / 128, DM / 128), 256, 0, stream>>>(feat_bf, wt_k, kn);

    // norms (+RoPE for K)
    ln_q<<<MQ, 256, 0, stream>>>(qn, q_w);
    rope_ln_k<<<MK, 256, 0, stream>>>(kn, fpos, k_w);

    // V transpose (overwrites feat_bf overlay — feat_bf dead after K-proj)
    transpose_v<<<dim3(23, NH, T_N), 256, 0, stream>>>(features, vt);

    // attention -> sampled (reuses tok_bf region)
    __bf16* sampled = tok_bf;
    attn<<<T_N * NH * (M_N / 128), 256, 0, stream>>>(qn, kn, vt, tracks, fpos, sampled);

    // output projection -> d_out (fp32)
    gemm_bt<false><<<dim3(MQ / 128, DM / 128), 256, 0, stream>>>(sampled, wt_o, d_out);
}